// Round 10
// baseline (172.296 us; speedup 1.0000x reference)
//
#include <hip/hip_runtime.h>
#include <math.h>
#include <stdint.h>

#ifndef TAU_CONST
#define TAU_CONST 1.0f
#endif

// ---------------- math (unchanged) ----------------

__device__ __forceinline__ void rbox_to_gauss(float x, float y, float w, float h, float r,
                                              float& mx, float& my,
                                              float& s00, float& s01, float& s11, float& det) {
    w = fminf(fmaxf(w, 1e-7f), 1e7f);
    h = fminf(fmaxf(h, 1e-7f), 1e7f);
    float a = 0.25f * w * w;   // (w/2)^2
    float b = 0.25f * h * h;   // (h/2)^2
    float s2, c2;
    __sincosf(r + r, &s2, &c2);          // sin 2r, cos 2r
    float hs = 0.5f * (a + b);
    float hd = 0.5f * (a - b);
    s00 = fmaf(hd, c2, hs);
    s11 = fmaf(-hd, c2, hs);
    s01 = hd * s2;
    det = a * b;                          // det(R S R^T) == a*b exactly
    mx = x; my = y;
}

__device__ __forceinline__ float kld_row(const float* p, const float* t) {
    float pmx, pmy, p00, p01, p11, dp;
    float tmx, tmy, t00, t01, t11, dt;
    rbox_to_gauss(p[0], p[1], p[2], p[3], p[4], pmx, pmy, p00, p01, p11, dp);
    rbox_to_gauss(t[0], t[1], t[2], t[3], t[4], tmx, tmy, t00, t01, t11, dt);
    float dx = pmx - tmx, dy = pmy - tmy;
    float inv_dt = __builtin_amdgcn_rcpf(dt);
    float inv_dp = __builtin_amdgcn_rcpf(dp);
    float term1 = (dx * dx * t11 - 2.0f * dx * dy * t01 + dy * dy * t00) * inv_dt;
    float tr = (t11 * p00 + t00 * p11 - 2.0f * t01 * p01) * inv_dt;
    float term2 = tr + __logf(dt * inv_dp);
    float dis = term1 + term2 - 2.0f;
    float kl = fmaxf(dis, 1e-6f);
    float l1p = __logf(1.0f + kl);
    return 1.0f - __builtin_amdgcn_rcpf(TAU_CONST + l1p);
}

// ---------- ASYMMETRIC cache policy on the round-6 persistent pipeline ----------
// Identical structure to the best kernel (persistent, double-buffered, LDS-DMA).
// ONLY change: per-input cache policy.
//   pred   -> NT (aux=2): streams from HBM, allocates nothing (no churn)
//   target -> cached (aux=0): allocates into L2/L3; 80 MB/iter halves the
//             allocation pressure that caused the pre-NT churn serializer, and
//             most of target should survive each iteration in the 256 MB LLC
//             (pre-NT FETCH=78 MB proved ~82 MB/iter survives even at 2x pressure).
// Reads then draw from two pools concurrently: HBM (~3.2 TB/s cap) + LLC.

__device__ __forceinline__ void gload_lds16_nt(const void* g, void* l) {
    __builtin_amdgcn_global_load_lds((const __attribute__((address_space(1))) uint32_t*)g,
                                     (__attribute__((address_space(3))) uint32_t*)l,
                                     16, 0, /*aux: NT*/ 2);
}
__device__ __forceinline__ void gload_lds16_cached(const void* g, void* l) {
    __builtin_amdgcn_global_load_lds((const __attribute__((address_space(1))) uint32_t*)g,
                                     (__attribute__((address_space(3))) uint32_t*)l,
                                     16, 0, /*aux: cached*/ 0);
}

#define ROWS_PER_TILE 256
#define FLOATS_PER_TILE (ROWS_PER_TILE * 5)   // 1280 floats per input per tile

__global__ void __launch_bounds__(256, 8)
gdloss_asym_kernel(const float* __restrict__ pred,
                   const float* __restrict__ target,
                   float* __restrict__ out, int ntiles) {
    __shared__ float lds[2][2 * FLOATS_PER_TILE];  // [buf][pred 1280 | tgt 1280]
    const int tid = threadIdx.x;
    const int wv  = tid >> 6;
    const int ln  = tid & 63;
    const int stride = gridDim.x;

    int t = blockIdx.x;
    // prologue: stage first tile into buf 0
    if (t < ntiles) {
        for (int c = wv; c < 10; c += 4) {   // chunk c: c<5 pred (NT), c>=5 tgt (cached)
            if (c < 5) {
                gload_lds16_nt(pred + (long long)t * FLOATS_PER_TILE + c * 256 + ln * 4,
                               &lds[0][c * 256]);
            } else {
                gload_lds16_cached(target + (long long)t * FLOATS_PER_TILE + (c - 5) * 256 + ln * 4,
                                   &lds[0][c * 256]);
            }
        }
    }

    int buf = 0;
    for (; t < ntiles; t += stride) {
        __syncthreads();                     // tile t staged (vmcnt drain + barrier)
        int tn = t + stride;
        if (tn < ntiles) {                   // issue next tile into buf^1, overlaps compute
            for (int c = wv; c < 10; c += 4) {
                if (c < 5) {
                    gload_lds16_nt(pred + (long long)tn * FLOATS_PER_TILE + c * 256 + ln * 4,
                                   &lds[buf ^ 1][c * 256]);
                } else {
                    gload_lds16_cached(target + (long long)tn * FLOATS_PER_TILE + (c - 5) * 256 + ln * 4,
                                       &lds[buf ^ 1][c * 256]);
                }
            }
        }
        // compute tile t: one row/thread, 5 consecutive floats at 5*tid
        // bank = (5*lane + k) mod 32, gcd(5,32)=1 -> 2 lanes/bank = free (measured 0)
        const float* lp = &lds[buf][5 * tid];
        const float* lt = &lds[buf][FLOATS_PER_TILE + 5 * tid];
        float p[5], tt[5];
#pragma unroll
        for (int k = 0; k < 5; ++k) { p[k] = lp[k]; tt[k] = lt[k]; }
        float r = kld_row(p, tt);
        __builtin_nontemporal_store(r, &out[(long long)t * ROWS_PER_TILE + tid]);
        buf ^= 1;
    }
}

// Scalar tail (rows not covered by full tiles; none at N=4M).
__global__ void gdloss_tail_kernel(const float* __restrict__ pred,
                                   const float* __restrict__ target,
                                   float* __restrict__ out, int start, int n) {
    int i = start + blockIdx.x * blockDim.x + threadIdx.x;
    if (i >= n) return;
    float p[5], t[5];
#pragma unroll
    for (int k = 0; k < 5; ++k) {
        p[k] = pred[5 * i + k];
        t[k] = target[5 * i + k];
    }
    out[i] = kld_row(p, t);
}

extern "C" void kernel_launch(void* const* d_in, const int* in_sizes, int n_in,
                              void* d_out, int out_size, void* d_ws, size_t ws_size,
                              hipStream_t stream) {
    const float* pred   = (const float*)d_in[0];
    const float* target = (const float*)d_in[1];
    float* out = (float*)d_out;
    int n      = in_sizes[0] / 5;          // rows
    int ntiles = n / ROWS_PER_TILE;
    if (ntiles > 0) {
        int blocks = ntiles < 2048 ? ntiles : 2048;   // 8 blocks/CU, persistent
        gdloss_asym_kernel<<<blocks, 256, 0, stream>>>(pred, target, out, ntiles);
    }
    int start = ntiles * ROWS_PER_TILE;
    int rem = n - start;
    if (rem > 0) {
        int tb = (rem + 255) / 256;
        gdloss_tail_kernel<<<tb, 256, 0, stream>>>(pred, target, out, start, n);
    }
}